// Round 2
// baseline (318.367 us; speedup 1.0000x reference)
//
#include <hip/hip_runtime.h>

// HashEmbeddingBag: out[b, j] = sum_{t in bag b} hashed_weight[(x[t]*64 + j) % HSIZE]
// HSIZE = 16,000,000 is divisible by DIM=64 so each virtual row is a contiguous
// 256B slice of hashed_weight -> wave-per-bag with lane=dim is fully coalesced.
// weight_idx input (d_in[1], 256 MB) is a pure function of the index; we compute
// it arithmetically instead of gathering it from HBM.
// Row base (x*64) % HSIZE is a multiple of 64 and <= HSIZE-64, so base+lane
// never wraps: one mod per index, contiguous 64-lane read.

#define DIM 64
#define HSIZE 16000000

__global__ __launch_bounds__(256) void hash_embedding_bag_kernel(
    const float* __restrict__ hashed_weight,
    const int* __restrict__ x,
    const int* __restrict__ offsets,
    float* __restrict__ out,
    int num_bags, int total)
{
    const int wave = threadIdx.x >> 6;           // 4 waves per block
    const int lane = threadIdx.x & 63;           // lane = output dim
    const int bag  = blockIdx.x * 4 + wave;
    if (bag >= num_bags) return;

    const int start = offsets[bag];
    const int end   = (bag + 1 < num_bags) ? offsets[bag + 1] : total;
    const int n     = end - start;

    float acc = 0.0f;
    int t = 0;
    // unroll x5: bag length is 50, so the unrolled loop covers the whole bag
    // with 5 independent gathers in flight to hide L2/L3-hit latency.
    for (; t + 5 <= n; t += 5) {
        int b0 = (x[start + t + 0] * DIM) % HSIZE;
        int b1 = (x[start + t + 1] * DIM) % HSIZE;
        int b2 = (x[start + t + 2] * DIM) % HSIZE;
        int b3 = (x[start + t + 3] * DIM) % HSIZE;
        int b4 = (x[start + t + 4] * DIM) % HSIZE;
        float v0 = hashed_weight[b0 + lane];
        float v1 = hashed_weight[b1 + lane];
        float v2 = hashed_weight[b2 + lane];
        float v3 = hashed_weight[b3 + lane];
        float v4 = hashed_weight[b4 + lane];
        acc += v0 + v1 + v2 + v3 + v4;
    }
    for (; t < n; ++t) {
        int b0 = (x[start + t] * DIM) % HSIZE;
        acc += hashed_weight[b0 + lane];
    }

    out[bag * DIM + lane] = acc;
}

extern "C" void kernel_launch(void* const* d_in, const int* in_sizes, int n_in,
                              void* d_out, int out_size, void* d_ws, size_t ws_size,
                              hipStream_t stream) {
    const float* hashed_weight = (const float*)d_in[0];
    // d_in[1] = weight_idx (computed arithmetically; not read)
    const int* x       = (const int*)d_in[2];
    const int* offsets = (const int*)d_in[3];
    float* out = (float*)d_out;

    const int total    = in_sizes[2];
    const int num_bags = in_sizes[3];

    const int waves_per_block = 4;
    const int blocks = (num_bags + waves_per_block - 1) / waves_per_block;
    hash_embedding_bag_kernel<<<blocks, waves_per_block * 64, 0, stream>>>(
        hashed_weight, x, offsets, out, num_bags, total);
}